// Round 1
// baseline (349.777 us; speedup 1.0000x reference)
//
#include <hip/hip_runtime.h>

#define SZ 4096

typedef unsigned short u16;
typedef __attribute__((ext_vector_type(4))) float f32x4;
typedef __attribute__((ext_vector_type(8))) short bf16x8;
typedef __attribute__((ext_vector_type(8))) unsigned short u16x8;
typedef __attribute__((ext_vector_type(4))) unsigned short u16x4;

static __device__ __forceinline__ u16 f2bf(float f) {
  // round-to-nearest-even f32 -> bf16 (inputs are finite; no NaN handling needed)
  union { float f; unsigned u; } v;
  v.f = f;
  unsigned r = v.u + 0x7fffu + ((v.u >> 16) & 1u);
  return (u16)(r >> 16);
}

// async global->LDS, 16B per lane; LDS dest must be wave-uniform base (HW adds lane*16)
#define ASYNC_COPY16(gsrc, ldst)                                               \
  __builtin_amdgcn_global_load_lds(                                            \
      (const __attribute__((address_space(1))) unsigned int*)(gsrc),           \
      (__attribute__((address_space(3))) unsigned int*)(ldst), 16, 0, 0)

// ---------- pass 1a: x fp32 [4096][4096] -> bf16 bits, same layout ----------
__global__ __launch_bounds__(256) void cvt_x_kernel(const float* __restrict__ in,
                                                    u16* __restrict__ out) {
  size_t i = ((size_t)blockIdx.x * 256 + threadIdx.x) * 8;
  f32x4 a = *(const f32x4*)(in + i);
  f32x4 b = *(const f32x4*)(in + i + 4);
  u16x8 o;
  o[0] = f2bf(a[0]); o[1] = f2bf(a[1]); o[2] = f2bf(a[2]); o[3] = f2bf(a[3]);
  o[4] = f2bf(b[0]); o[5] = f2bf(b[1]); o[6] = f2bf(b[2]); o[7] = f2bf(b[3]);
  *(u16x8*)(out + i) = o;
}

// ---------- pass 1b: W fp32 [K][N] -> Wt bf16 [N][K] (transpose+convert) ----------
__global__ __launch_bounds__(256) void cvt_wt_kernel(const float* __restrict__ W,
                                                     u16* __restrict__ Wt) {
  __shared__ float t[64][65];  // +1 pad: conflict-free transposed reads
  const int tid = threadIdx.x;
  const int tr = tid >> 4, tc = tid & 15;
  const size_t k0 = (size_t)blockIdx.y * 64;
  const size_t n0 = (size_t)blockIdx.x * 64;
#pragma unroll
  for (int i = 0; i < 4; ++i) {
    int k = i * 16 + tr;
    f32x4 v = *(const f32x4*)&W[(k0 + k) * SZ + n0 + tc * 4];
    t[k][tc * 4 + 0] = v[0]; t[k][tc * 4 + 1] = v[1];
    t[k][tc * 4 + 2] = v[2]; t[k][tc * 4 + 3] = v[3];
  }
  __syncthreads();
#pragma unroll
  for (int i = 0; i < 4; ++i) {
    int n = i * 16 + tr;
    u16x4 o;
    o[0] = f2bf(t[tc * 4 + 0][n]);
    o[1] = f2bf(t[tc * 4 + 1][n]);
    o[2] = f2bf(t[tc * 4 + 2][n]);
    o[3] = f2bf(t[tc * 4 + 3][n]);
    *(u16x4*)&Wt[(n0 + n) * SZ + k0 + tc * 4] = o;
  }
}

// ---------- pass 2: bf16 GEMM, m97 structure ----------
// C[m][n] = sum_k A[m][k] * Bt[n][k]  (+ bias[n])
// 128x128 tile, BK=64, 256 threads = 4 waves in 2x2, each wave 64x64 = 4x4 MFMA frags
__global__ __launch_bounds__(256) void gemm_kernel(const u16* __restrict__ pA,
                                                   const u16* __restrict__ pB,
                                                   const float* __restrict__ bias,
                                                   float* __restrict__ C) {
  __shared__ alignas(16) u16 As[128 * 64];
  __shared__ alignas(16) u16 Bs[128 * 64];

  const int tid = threadIdx.x;
  const int wave = tid >> 6, lane = tid & 63;
  const int wr = wave >> 1, wc = wave & 1;
  const size_t m0 = (size_t)blockIdx.y * 128;
  const size_t n0 = (size_t)blockIdx.x * 128;

  f32x4 acc[4][4] = {};

  // staging geometry: element e = j*2048 + wave*512 + lane*8 within the 128x64 tile
  // row = e>>6, col = e&63  ->  row = j*32 + wave*8 + (lane>>3), col = (lane&7)*8
  const int srow = wave * 8 + (lane >> 3);
  const int scol = (lane & 7) * 8;
  const u16* aptr = pA + (m0 + srow) * SZ + scol;
  const u16* bptr = pB + (n0 + srow) * SZ + scol;

  for (int k0 = 0; k0 < SZ; k0 += 64) {
#pragma unroll
    for (int j = 0; j < 4; ++j) {
      ASYNC_COPY16(aptr + (size_t)(j * 32) * SZ + k0, &As[j * 2048 + wave * 512]);
      ASYNC_COPY16(bptr + (size_t)(j * 32) * SZ + k0, &Bs[j * 2048 + wave * 512]);
    }
    __syncthreads();  // compiler drains vmcnt before s_barrier

#pragma unroll
    for (int kk = 0; kk < 2; ++kk) {
      bf16x8 af[4], bfr[4];
#pragma unroll
      for (int m = 0; m < 4; ++m)
        af[m] = *(const bf16x8*)&As[(wr * 64 + m * 16 + (lane & 15)) * 64 + kk * 32 + (lane >> 4) * 8];
#pragma unroll
      for (int n = 0; n < 4; ++n)
        bfr[n] = *(const bf16x8*)&Bs[(wc * 64 + n * 16 + (lane & 15)) * 64 + kk * 32 + (lane >> 4) * 8];
#pragma unroll
      for (int m = 0; m < 4; ++m)
#pragma unroll
        for (int n = 0; n < 4; ++n)
          acc[m][n] = __builtin_amdgcn_mfma_f32_16x16x32_bf16(af[m], bfr[n], acc[m][n], 0, 0, 0);
    }
    __syncthreads();
  }

  // epilogue: C/D layout col = lane&15, row = (lane>>4)*4 + reg
#pragma unroll
  for (int n = 0; n < 4; ++n) {
    const size_t col = n0 + wc * 64 + n * 16 + (lane & 15);
    const float bv = bias[col];
#pragma unroll
    for (int m = 0; m < 4; ++m) {
      const size_t row0 = m0 + wr * 64 + m * 16 + (lane >> 4) * 4;
#pragma unroll
      for (int r = 0; r < 4; ++r)
        C[(row0 + r) * SZ + col] = acc[m][n][r] + bv;
    }
  }
}

// ---------- safety net if workspace is too small: correct, slow fp32 path ----------
__global__ __launch_bounds__(256) void gemm_fallback(const float* __restrict__ x,
                                                     const float* __restrict__ w,
                                                     const float* __restrict__ bias,
                                                     float* __restrict__ out) {
  const int col = blockIdx.x * 256 + threadIdx.x;
  const int row = blockIdx.y;
  const float* xr = x + (size_t)row * SZ;
  float s = 0.f;
  for (int i = 0; i < SZ; ++i) s = fmaf(xr[i], w[(size_t)i * SZ + col], s);
  out[(size_t)row * SZ + col] = s + bias[col];
}

extern "C" void kernel_launch(void* const* d_in, const int* in_sizes, int n_in,
                              void* d_out, int out_size, void* d_ws, size_t ws_size,
                              hipStream_t stream) {
  const float* x = (const float*)d_in[0];
  const float* w = (const float*)d_in[1];   // [1][IN][OUT] -> [4096][4096], W[k][n]
  const float* b = (const float*)d_in[2];   // [1][OUT] -> [4096]
  float* out = (float*)d_out;

  const size_t need = (size_t)SZ * SZ * 2 * 2;  // x_bf16 (32MB) + Wt_bf16 (32MB)
  if (ws_size >= need) {
    u16* xb = (u16*)d_ws;
    u16* wt = xb + (size_t)SZ * SZ;
    cvt_x_kernel<<<SZ * SZ / 2048, 256, 0, stream>>>(x, xb);
    cvt_wt_kernel<<<dim3(SZ / 64, SZ / 64), 256, 0, stream>>>(w, wt);
    gemm_kernel<<<dim3(SZ / 128, SZ / 128), 256, 0, stream>>>(xb, wt, b, out);
  } else {
    gemm_fallback<<<dim3(SZ / 256, SZ), 256, 0, stream>>>(x, w, b, out);
  }
}

// Round 2
// 299.609 us; speedup vs baseline: 1.1674x; 1.1674x over previous
//
#include <hip/hip_runtime.h>

#define SZ 4096
#define NT 64  // K-tiles of BK=64

typedef unsigned short u16;
typedef __attribute__((ext_vector_type(4))) float f32x4;
typedef __attribute__((ext_vector_type(8))) short bf16x8;
typedef __attribute__((ext_vector_type(8))) unsigned short u16x8;
typedef __attribute__((ext_vector_type(4))) unsigned short u16x4;

static __device__ __forceinline__ u16 f2bf(float f) {
  union { float f; unsigned u; } v;
  v.f = f;
  unsigned r = v.u + 0x7fffu + ((v.u >> 16) & 1u);
  return (u16)(r >> 16);
}

#define ASYNC_COPY16(gsrc, ldst)                                               \
  __builtin_amdgcn_global_load_lds(                                            \
      (const __attribute__((address_space(1))) unsigned int*)(gsrc),           \
      (__attribute__((address_space(3))) unsigned int*)(ldst), 16, 0, 0)

#define BARRIER() asm volatile("s_barrier" ::: "memory")
#define WAIT_LGKM0() asm volatile("s_waitcnt lgkmcnt(0)" ::: "memory")

// ---------- pre-pass: x -> bf16 (linear) and W [K][N] -> Wt bf16 [N][K], one launch ----------
__global__ __launch_bounds__(256) void prep_kernel(const float* __restrict__ x,
                                                   const float* __restrict__ W,
                                                   u16* __restrict__ xb,
                                                   u16* __restrict__ wt) {
  __shared__ float t[64][65];
  const int b = blockIdx.x;
  const int tid = threadIdx.x;
  if (b < 8192) {
    size_t i = ((size_t)b * 256 + tid) * 8;
    f32x4 a = *(const f32x4*)(x + i);
    f32x4 c = *(const f32x4*)(x + i + 4);
    u16x8 o;
    o[0] = f2bf(a[0]); o[1] = f2bf(a[1]); o[2] = f2bf(a[2]); o[3] = f2bf(a[3]);
    o[4] = f2bf(c[0]); o[5] = f2bf(c[1]); o[6] = f2bf(c[2]); o[7] = f2bf(c[3]);
    *(u16x8*)(xb + i) = o;
  } else {
    const int id = b - 8192;
    const size_t n0 = (size_t)(id & 63) * 64;
    const size_t k0 = (size_t)(id >> 6) * 64;
    const int tr = tid >> 4, tc = tid & 15;
#pragma unroll
    for (int i = 0; i < 4; ++i) {
      int k = i * 16 + tr;
      f32x4 v = *(const f32x4*)&W[(k0 + k) * SZ + n0 + tc * 4];
      t[k][tc * 4 + 0] = v[0]; t[k][tc * 4 + 1] = v[1];
      t[k][tc * 4 + 2] = v[2]; t[k][tc * 4 + 3] = v[3];
    }
    __syncthreads();
#pragma unroll
    for (int i = 0; i < 4; ++i) {
      int n = i * 16 + tr;
      u16x4 o;
      o[0] = f2bf(t[tc * 4 + 0][n]);
      o[1] = f2bf(t[tc * 4 + 1][n]);
      o[2] = f2bf(t[tc * 4 + 2][n]);
      o[3] = f2bf(t[tc * 4 + 3][n]);
      *(u16x4*)&wt[(n0 + n) * SZ + k0 + tc * 4] = o;
    }
  }
}

// ---------- 256x256 bf16 GEMM, 8-wave, K-half ring, counted vmcnt ----------
// C[m][n] = sum_k A[m][k] * Bt[n][k] + bias[n]
__global__ __launch_bounds__(512, 2) void gemm_kernel(const u16* __restrict__ pA,
                                                      const u16* __restrict__ pB,
                                                      const float* __restrict__ bias,
                                                      float* __restrict__ C) {
  // [dbuf][khalf][256 rows x 32 cols], rows 64 B; swizzle: byte ^= (row&3)<<4
  __shared__ u16 As[2][2][256 * 32];
  __shared__ u16 Bs[2][2][256 * 32];

  const int tid = threadIdx.x;
  const int w = tid >> 6, lane = tid & 63;
  const int wr = w >> 2, wc = w & 3;      // wave grid 2 (M) x 4 (N)
  const int ln15 = lane & 15, hi = lane >> 4;

  // XCD-aware swizzle: 256 blocks -> 8 XCD clusters of 4(by) x 8(bx) tiles
  const int bid = blockIdx.x;
  const int xcd = bid & 7, loc = bid >> 3;
  const int by = (xcd >> 1) * 4 + (loc & 3);
  const int bx = (xcd & 1) * 8 + (loc >> 2);
  const size_t m0 = (size_t)by * 256;
  const size_t n0 = (size_t)bx * 256;

  // staging: thread tid covers LDS bytes (r*512+tid)*16 of a 16KB half
  //   row = r*128 + (tid>>2), src col pre-inverse-swizzled
  const int srow = tid >> 2;                                  // 0..127
  const int scol = (((tid & 3) ^ ((tid >> 2) & 3)) << 3);     // elems
  const u16* aS = pA + (m0 + srow) * SZ + scol;
  const u16* bS = pB + (n0 + srow) * SZ + scol;
  const int dOff = w * 1024;                                  // bytes

#define STAGE_A(t_, kh_) do {                                                  \
    const u16* s_ = aS + (size_t)(t_) * 64 + (kh_) * 32;                       \
    char* d_ = (char*)(&As[(t_) & 1][kh_][0]) + dOff;                          \
    ASYNC_COPY16(s_, d_);                                                      \
    ASYNC_COPY16(s_ + (size_t)128 * SZ, d_ + 8192);                            \
  } while (0)
#define STAGE_B(t_, kh_) do {                                                  \
    const u16* s_ = bS + (size_t)(t_) * 64 + (kh_) * 32;                       \
    char* d_ = (char*)(&Bs[(t_) & 1][kh_][0]) + dOff;                          \
    ASYNC_COPY16(s_, d_);                                                      \
    ASYNC_COPY16(s_ + (size_t)128 * SZ, d_ + 8192);                            \
  } while (0)

  // fragment read: lane reads row rowbase+i*16+ln15, 16B at col hi*16, swizzled
#define LDFRAG(dst_, base_, rowbase_) do {                                     \
    _Pragma("unroll")                                                          \
    for (int i_ = 0; i_ < 4; ++i_) {                                           \
      int row_ = (rowbase_) + i_ * 16 + ln15;                                  \
      int off_ = ((row_ << 6) + (hi << 4)) ^ ((row_ & 3) << 4);                \
      dst_[i_] = *(const bf16x8*)((const char*)(base_) + off_);                \
    }                                                                          \
  } while (0)

#define MFMA16(mb_) do {                                                       \
    __builtin_amdgcn_s_setprio(1);                                             \
    _Pragma("unroll")                                                          \
    for (int i_ = 0; i_ < 4; ++i_)                                             \
      _Pragma("unroll")                                                        \
      for (int n_ = 0; n_ < 4; ++n_)                                           \
        acc[(mb_) + i_][n_] = __builtin_amdgcn_mfma_f32_16x16x32_bf16(         \
            af[i_], bfr[n_], acc[(mb_) + i_][n_], 0, 0, 0);                    \
    __builtin_amdgcn_s_setprio(0);                                             \
  } while (0)

  f32x4 acc[8][4] = {};

  // prologue: tile0 all 4 halves + tile1 kh0 halves; wait tile0 landed (4 loads left)
  STAGE_A(0, 0); STAGE_B(0, 0); STAGE_A(0, 1); STAGE_B(0, 1);
  STAGE_A(1, 0); STAGE_B(1, 0);
  asm volatile("s_waitcnt vmcnt(4)" ::: "memory");
  BARRIER();

  for (int t = 0; t < NT; ++t) {
    const int buf = t & 1;
    bf16x8 af[4], bfr[4];

    // ---- phase 0: kh0, m-frags 0-3 (+ B-frags kh0); stage A(t+1,kh1)
    LDFRAG(bfr, &Bs[buf][0][0], wc * 64);
    LDFRAG(af, &As[buf][0][0], wr * 128);
    if (t + 1 < NT) STAGE_A(t + 1, 1);
    BARRIER(); WAIT_LGKM0();
    MFMA16(0);
    BARRIER();

    // ---- phase 1: kh0, m-frags 4-7; stage B(t+1,kh1); wait for (t)kh1
    LDFRAG(af, &As[buf][0][0], wr * 128 + 64);
    if (t + 1 < NT) STAGE_B(t + 1, 1);
    if (t + 1 < NT) asm volatile("s_waitcnt vmcnt(8)" ::: "memory");
    else            asm volatile("s_waitcnt vmcnt(0)" ::: "memory");
    BARRIER(); WAIT_LGKM0();
    MFMA16(4);
    BARRIER();

    // ---- phase 2: kh1, m-frags 0-3 (+ B-frags kh1); stage A(t+2,kh0)
    //      (slot [t&1][kh0] was cleared by the phase-1-end barrier)
    LDFRAG(bfr, &Bs[buf][1][0], wc * 64);
    LDFRAG(af, &As[buf][1][0], wr * 128);
    if (t + 2 < NT) STAGE_A(t + 2, 0);
    BARRIER(); WAIT_LGKM0();
    MFMA16(0);
    BARRIER();

    // ---- phase 3: kh1, m-frags 4-7; stage B(t+2,kh0); wait for (t+1)kh0
    LDFRAG(af, &As[buf][1][0], wr * 128 + 64);
    if (t + 2 < NT) STAGE_B(t + 2, 0);
    if (t + 2 < NT)      asm volatile("s_waitcnt vmcnt(8)" ::: "memory");
    else if (t + 1 < NT) asm volatile("s_waitcnt vmcnt(4)" ::: "memory");
    BARRIER(); WAIT_LGKM0();
    MFMA16(4);
    BARRIER();
  }

  // epilogue: C/D map col=lane&15, row=(lane>>4)*4+reg
  float bv[4];
#pragma unroll
  for (int n = 0; n < 4; ++n) bv[n] = bias[n0 + wc * 64 + n * 16 + ln15];
#pragma unroll
  for (int m = 0; m < 8; ++m) {
    const size_t row0 = m0 + wr * 128 + m * 16 + hi * 4;
#pragma unroll
    for (int n = 0; n < 4; ++n) {
      const size_t col = n0 + wc * 64 + n * 16 + ln15;
#pragma unroll
      for (int r = 0; r < 4; ++r)
        C[(row0 + r) * SZ + col] = acc[m][n][r] + bv[n];
    }
  }
#undef STAGE_A
#undef STAGE_B
#undef LDFRAG
#undef MFMA16
}

// ---------- fallback if workspace too small ----------
__global__ __launch_bounds__(256) void gemm_fallback(const float* __restrict__ x,
                                                     const float* __restrict__ w,
                                                     const float* __restrict__ bias,
                                                     float* __restrict__ out) {
  const int col = blockIdx.x * 256 + threadIdx.x;
  const int row = blockIdx.y;
  const float* xr = x + (size_t)row * SZ;
  float s = 0.f;
  for (int i = 0; i < SZ; ++i) s = fmaf(xr[i], w[(size_t)i * SZ + col], s);
  out[(size_t)row * SZ + col] = s + bias[col];
}

extern "C" void kernel_launch(void* const* d_in, const int* in_sizes, int n_in,
                              void* d_out, int out_size, void* d_ws, size_t ws_size,
                              hipStream_t stream) {
  const float* x = (const float*)d_in[0];
  const float* w = (const float*)d_in[1];
  const float* b = (const float*)d_in[2];
  float* out = (float*)d_out;

  const size_t need = (size_t)SZ * SZ * 2 * 2;
  if (ws_size >= need) {
    u16* xb = (u16*)d_ws;
    u16* wt = xb + (size_t)SZ * SZ;
    prep_kernel<<<12288, 256, 0, stream>>>(x, w, xb, wt);
    gemm_kernel<<<256, 512, 0, stream>>>(xb, wt, b, out);
  } else {
    gemm_fallback<<<dim3(SZ / 256, SZ), 256, 0, stream>>>(x, w, b, out);
  }
}

// Round 3
// 298.690 us; speedup vs baseline: 1.1710x; 1.0031x over previous
//
#include <hip/hip_runtime.h>

#define SZ 4096
#define NT 64  // K-tiles of BK=64

typedef unsigned short u16;
typedef __attribute__((ext_vector_type(4))) float f32x4;
typedef __attribute__((ext_vector_type(8))) short bf16x8;
typedef __attribute__((ext_vector_type(8))) unsigned short u16x8;
typedef __attribute__((ext_vector_type(4))) unsigned short u16x4;

static __device__ __forceinline__ u16 f2bf(float f) {
  union { float f; unsigned u; } v;
  v.f = f;
  unsigned r = v.u + 0x7fffu + ((v.u >> 16) & 1u);
  return (u16)(r >> 16);
}

#define ASYNC_COPY16(gsrc, ldst)                                               \
  __builtin_amdgcn_global_load_lds(                                            \
      (const __attribute__((address_space(1))) unsigned int*)(gsrc),           \
      (__attribute__((address_space(3))) unsigned int*)(ldst), 16, 0, 0)

#define BARRIER() asm volatile("s_barrier" ::: "memory")
#define WAIT_LGKM0() asm volatile("s_waitcnt lgkmcnt(0)" ::: "memory")

// ---------- pre-pass: x -> bf16 (linear) and W [K][N] -> Wt bf16 [N][K] ----------
__global__ __launch_bounds__(256) void prep_kernel(const float* __restrict__ x,
                                                   const float* __restrict__ W,
                                                   u16* __restrict__ xb,
                                                   u16* __restrict__ wt) {
  __shared__ float t[64][65];
  const int b = blockIdx.x;
  const int tid = threadIdx.x;
  if (b < 8192) {
    size_t i = ((size_t)b * 256 + tid) * 8;
    f32x4 a = *(const f32x4*)(x + i);
    f32x4 c = *(const f32x4*)(x + i + 4);
    u16x8 o;
    o[0] = f2bf(a[0]); o[1] = f2bf(a[1]); o[2] = f2bf(a[2]); o[3] = f2bf(a[3]);
    o[4] = f2bf(c[0]); o[5] = f2bf(c[1]); o[6] = f2bf(c[2]); o[7] = f2bf(c[3]);
    *(u16x8*)(xb + i) = o;
  } else {
    const int id = b - 8192;
    const size_t n0 = (size_t)(id & 63) * 64;
    const size_t k0 = (size_t)(id >> 6) * 64;
    const int tr = tid >> 4, tc = tid & 15;
#pragma unroll
    for (int i = 0; i < 4; ++i) {
      int k = i * 16 + tr;
      f32x4 v = *(const f32x4*)&W[(k0 + k) * SZ + n0 + tc * 4];
      t[k][tc * 4 + 0] = v[0]; t[k][tc * 4 + 1] = v[1];
      t[k][tc * 4 + 2] = v[2]; t[k][tc * 4 + 3] = v[3];
    }
    __syncthreads();
#pragma unroll
    for (int i = 0; i < 4; ++i) {
      int n = i * 16 + tr;
      u16x4 o;
      o[0] = f2bf(t[tc * 4 + 0][n]);
      o[1] = f2bf(t[tc * 4 + 1][n]);
      o[2] = f2bf(t[tc * 4 + 2][n]);
      o[3] = f2bf(t[tc * 4 + 3][n]);
      *(u16x4*)&wt[(n0 + n) * SZ + k0 + tc * 4] = o;
    }
  }
}

// ---------- 256x256 bf16 GEMM, 8-wave, K-half ring, counted vmcnt ----------
// Swizzle (both sides, involution): LDS slot (bits 4-5) ^= (row&3)^((row>>2)&3).
// On reads this is a pure lane function -> hoisted; 8-lane groups hit all 32 banks.
__global__ __launch_bounds__(512, 2) void gemm_kernel(const u16* __restrict__ pA,
                                                      const u16* __restrict__ pB,
                                                      const float* __restrict__ bias,
                                                      float* __restrict__ C) {
  __shared__ u16 As[2][2][256 * 32];
  __shared__ u16 Bs[2][2][256 * 32];

  const int tid = threadIdx.x;
  const int w = tid >> 6, lane = tid & 63;
  const int wr = w >> 2, wc = w & 3;      // wave grid 2 (M) x 4 (N)
  const int ln15 = lane & 15, hi = lane >> 4;

  // XCD-aware swizzle: 256 blocks -> 8 XCD clusters of 4(by) x 8(bx) tiles
  const int bid = blockIdx.x;
  const int xcd = bid & 7, loc = bid >> 3;
  const int by = (xcd >> 1) * 4 + (loc & 3);
  const int bx = (xcd & 1) * 8 + (loc >> 2);
  const size_t m0 = (size_t)by * 256;
  const size_t n0 = (size_t)bx * 256;

  // staging: thread tid covers LDS bytes [tid*16, +16) of each 16KB half
  //   row = tid>>2; source col slot inverse-swizzled: slot ^ f(row)
  const int srow = tid >> 2;                                            // 0..127
  const int scol = (((tid & 3) ^ ((tid >> 2) & 3) ^ ((tid >> 4) & 3)) << 3);
  const u16* aS = pA + (m0 + srow) * SZ + scol;
  const u16* bS = pB + (n0 + srow) * SZ + scol;
  const int dOff = w * 1024;                                            // bytes

  // read-side lane offsets (swizzle folded in; constant over phases/frags)
  const int fl = ((lane & 3) ^ ((lane >> 2) & 3)) << 4;
  const int aoff = (((wr * 128 + ln15) << 6) | (hi << 4)) ^ fl;
  const int boff = (((wc * 64 + ln15) << 6) | (hi << 4)) ^ fl;

#define STAGE_A(t_, kh_) do {                                                  \
    const u16* s_ = aS + (size_t)(t_) * 64 + (kh_) * 32;                       \
    char* d_ = (char*)(&As[(t_) & 1][kh_][0]) + dOff;                          \
    ASYNC_COPY16(s_, d_);                                                      \
    ASYNC_COPY16(s_ + (size_t)128 * SZ, d_ + 8192);                            \
  } while (0)
#define STAGE_B(t_, kh_) do {                                                  \
    const u16* s_ = bS + (size_t)(t_) * 64 + (kh_) * 32;                       \
    char* d_ = (char*)(&Bs[(t_) & 1][kh_][0]) + dOff;                          \
    ASYNC_COPY16(s_, d_);                                                      \
    ASYNC_COPY16(s_ + (size_t)128 * SZ, d_ + 8192);                            \
  } while (0)

#define LDA4(dst_, buf_, kh_, extra_) do {                                     \
    const char* b_ = (const char*)(&As[buf_][kh_][0]) + aoff + (extra_);       \
    dst_[0] = *(const bf16x8*)(b_);                                            \
    dst_[1] = *(const bf16x8*)(b_ + 1024);                                     \
    dst_[2] = *(const bf16x8*)(b_ + 2048);                                     \
    dst_[3] = *(const bf16x8*)(b_ + 3072);                                     \
  } while (0)
#define LDB4(dst_, buf_, kh_) do {                                             \
    const char* b_ = (const char*)(&Bs[buf_][kh_][0]) + boff;                  \
    dst_[0] = *(const bf16x8*)(b_);                                            \
    dst_[1] = *(const bf16x8*)(b_ + 1024);                                     \
    dst_[2] = *(const bf16x8*)(b_ + 2048);                                     \
    dst_[3] = *(const bf16x8*)(b_ + 3072);                                     \
  } while (0)

#define MFMA16(mb_) do {                                                       \
    __builtin_amdgcn_s_setprio(1);                                             \
    _Pragma("unroll")                                                          \
    for (int i_ = 0; i_ < 4; ++i_)                                             \
      _Pragma("unroll")                                                        \
      for (int n_ = 0; n_ < 4; ++n_)                                           \
        acc[(mb_) + i_][n_] = __builtin_amdgcn_mfma_f32_16x16x32_bf16(         \
            af[i_], bfr[n_], acc[(mb_) + i_][n_], 0, 0, 0);                    \
    __builtin_amdgcn_s_setprio(0);                                             \
  } while (0)

  f32x4 acc[8][4] = {};

  // prologue: tile0 all 4 halves + tile1 kh0; wait tile0 landed (4 loads allowed out)
  STAGE_A(0, 0); STAGE_B(0, 0); STAGE_A(0, 1); STAGE_B(0, 1);
  STAGE_A(1, 0); STAGE_B(1, 0);
  asm volatile("s_waitcnt vmcnt(4)" ::: "memory");
  BARRIER();

  for (int t = 0; t < NT; ++t) {
    const int buf = t & 1;
    bf16x8 af[4], bfr[4];

    // ---- phase 0: kh0, m 0-3; stage A(t+1,kh1)
    if (t + 1 < NT) STAGE_A(t + 1, 1);
    LDB4(bfr, buf, 0);
    LDA4(af, buf, 0, 0);
    BARRIER(); WAIT_LGKM0();
    MFMA16(0);
    BARRIER();

    // ---- phase 1: kh0, m 4-7; stage B(t+1,kh1); ensure (t)kh1 landed
    if (t + 1 < NT) STAGE_B(t + 1, 1);
    LDA4(af, buf, 0, 4096);
    if (t + 1 < NT) asm volatile("s_waitcnt vmcnt(8)" ::: "memory");
    else            asm volatile("s_waitcnt vmcnt(0)" ::: "memory");
    BARRIER(); WAIT_LGKM0();
    MFMA16(4);
    BARRIER();

    // ---- phase 2: kh1, m 0-3; stage A(t+2,kh0) (slot freed by phase-1 barrier)
    if (t + 2 < NT) STAGE_A(t + 2, 0);
    LDB4(bfr, buf, 1);
    LDA4(af, buf, 1, 0);
    BARRIER(); WAIT_LGKM0();
    MFMA16(0);
    BARRIER();

    // ---- phase 3: kh1, m 4-7; stage B(t+2,kh0); ensure (t+1)kh0 landed
    if (t + 2 < NT) STAGE_B(t + 2, 0);
    LDA4(af, buf, 1, 4096);
    if (t + 2 < NT)      asm volatile("s_waitcnt vmcnt(8)" ::: "memory");
    else if (t + 1 < NT) asm volatile("s_waitcnt vmcnt(4)" ::: "memory");
    BARRIER(); WAIT_LGKM0();
    MFMA16(4);
    BARRIER();
  }

  // epilogue: C/D map col=lane&15, row=(lane>>4)*4+reg
  float bv[4];
#pragma unroll
  for (int n = 0; n < 4; ++n) bv[n] = bias[n0 + wc * 64 + n * 16 + ln15];
#pragma unroll
  for (int m = 0; m < 8; ++m) {
    const size_t row0 = m0 + wr * 128 + m * 16 + hi * 4;
#pragma unroll
    for (int n = 0; n < 4; ++n) {
      const size_t col = n0 + wc * 64 + n * 16 + ln15;
#pragma unroll
      for (int r = 0; r < 4; ++r)
        C[(row0 + r) * SZ + col] = acc[m][n][r] + bv[n];
    }
  }
#undef STAGE_A
#undef STAGE_B
#undef LDA4
#undef LDB4
#undef MFMA16
}

// ---------- fallback if workspace too small ----------
__global__ __launch_bounds__(256) void gemm_fallback(const float* __restrict__ x,
                                                     const float* __restrict__ w,
                                                     const float* __restrict__ bias,
                                                     float* __restrict__ out) {
  const int col = blockIdx.x * 256 + threadIdx.x;
  const int row = blockIdx.y;
  const float* xr = x + (size_t)row * SZ;
  float s = 0.f;
  for (int i = 0; i < SZ; ++i) s = fmaf(xr[i], w[(size_t)i * SZ + col], s);
  out[(size_t)row * SZ + col] = s + bias[col];
}

extern "C" void kernel_launch(void* const* d_in, const int* in_sizes, int n_in,
                              void* d_out, int out_size, void* d_ws, size_t ws_size,
                              hipStream_t stream) {
  const float* x = (const float*)d_in[0];
  const float* w = (const float*)d_in[1];
  const float* b = (const float*)d_in[2];
  float* out = (float*)d_out;

  const size_t need = (size_t)SZ * SZ * 2 * 2;
  if (ws_size >= need) {
    u16* xb = (u16*)d_ws;
    u16* wt = xb + (size_t)SZ * SZ;
    prep_kernel<<<12288, 256, 0, stream>>>(x, w, xb, wt);
    gemm_kernel<<<256, 512, 0, stream>>>(xb, wt, b, out);
  } else {
    gemm_fallback<<<dim3(SZ / 256, SZ), 256, 0, stream>>>(x, w, b, out);
  }
}